// Round 10
// baseline (393.895 us; speedup 1.0000x reference)
//
#include <hip/hip_runtime.h>
#include <hip/hip_bf16.h>

#define N_NODES  100000
#define E_EDGES  50000
#define U_NODES  50000
#define D        128
#define NPE      32
#define NSLICE   8
#define SLICE_COLS 16   // D / NSLICE, 32 B bf16 per row-slice

typedef __attribute__((ext_vector_type(8))) short short8;       // 8 bf16
typedef __attribute__((ext_vector_type(4))) unsigned short u16x4;
typedef __attribute__((ext_vector_type(4))) float f32x4;
typedef __attribute__((ext_vector_type(4))) int i32x4;

// f32 -> bf16 bits, round-to-nearest-even (finite inputs only)
static __device__ __forceinline__ unsigned short f2bf_bits(float f) {
    unsigned u = __float_as_uint(f);
    return (unsigned short)((u + 0x7fffu + ((u >> 16) & 1u)) >> 16);
}

// XOR-swizzled LDS byte offset for [rows][128] bf16 tiles (256 B rows).
static __device__ __forceinline__ int swz(int row, int bytecol) {
    return row * 256 + ((((bytecol >> 4) ^ (row & 7)) << 4) | (bytecol & 15));
}

static __device__ __forceinline__ void acc8(const uint4 v, float w, float* a) {
    a[0] = fmaf(__uint_as_float(v.x << 16),         w, a[0]);
    a[1] = fmaf(__uint_as_float(v.x & 0xffff0000u), w, a[1]);
    a[2] = fmaf(__uint_as_float(v.y << 16),         w, a[2]);
    a[3] = fmaf(__uint_as_float(v.y & 0xffff0000u), w, a[3]);
    a[4] = fmaf(__uint_as_float(v.z << 16),         w, a[4]);
    a[5] = fmaf(__uint_as_float(v.z & 0xffff0000u), w, a[5]);
    a[6] = fmaf(__uint_as_float(v.w << 16),         w, a[6]);
    a[7] = fmaf(__uint_as_float(v.w & 0xffff0000u), w, a[7]);
}
static __device__ __forceinline__ void set8(const uint4 v, float* a) {
    a[0] = __uint_as_float(v.x << 16);  a[1] = __uint_as_float(v.x & 0xffff0000u);
    a[2] = __uint_as_float(v.y << 16);  a[3] = __uint_as_float(v.y & 0xffff0000u);
    a[4] = __uint_as_float(v.z << 16);  a[5] = __uint_as_float(v.z & 0xffff0000u);
    a[6] = __uint_as_float(v.w << 16);  a[7] = __uint_as_float(v.w & 0xffff0000u);
}

// ---------------------------------------------------------------------------
// Merged prep: blocks [0,128) transpose W1/W2 -> Wt bf16; rest convert x->xb.
// ---------------------------------------------------------------------------
__global__ __launch_bounds__(256) void prep(const float* __restrict__ w1,
                                            const float* __restrict__ w2,
                                            const float* __restrict__ x,
                                            unsigned short* __restrict__ wt,
                                            unsigned short* __restrict__ xb,
                                            int n8) {
    if (blockIdx.x < 128) {
        const int t = blockIdx.x * 256 + threadIdx.x;   // 0..32767
        const int which = t >> 14;
        const int e = t & 16383;
        const int k = e >> 7, c = e & 127;
        const float* w = which ? w2 : w1;
        wt[which * 16384 + c * 128 + k] = f2bf_bits(w[e]);
        return;
    }
    const int i = (blockIdx.x - 128) * 256 + threadIdx.x;
    if (i >= n8) return;
    const float4 a = ((const float4*)x)[2 * i];
    const float4 b = ((const float4*)x)[2 * i + 1];
    uint4 o;
    o.x = (unsigned)f2bf_bits(a.x) | ((unsigned)f2bf_bits(a.y) << 16);
    o.y = (unsigned)f2bf_bits(a.z) | ((unsigned)f2bf_bits(a.w) << 16);
    o.z = (unsigned)f2bf_bits(b.x) | ((unsigned)f2bf_bits(b.y) << 16);
    o.w = (unsigned)f2bf_bits(b.z) | ((unsigned)f2bf_bits(b.w) << 16);
    ((uint4*)xb)[i] = o;
}

// ---------------------------------------------------------------------------
// XCD-sliced gather + masked mean.
// Theory (r2/r4/r8/r9 counters): gathers are bound at ~3.3 TB/s of L2-miss
// (LLC fabric) traffic; table slices of 32 B/row fit one XCD's 4MB L2
// (gather1: 3.2 MB, gather2: 1.6 MB). slice = blockIdx&7 pins each slice to
// one XCD under measured round-robin dispatch (m09) — correctness does not
// depend on the mapping. Index stream (full 6.4 MB per XCD) is loaded
// nontemporal so it doesn't evict the table.
// Per wave: 32 edges (lane pair per edge), indices preloaded to regs
// (1 shfl_xor serves slots j and j+16), in-lane accumulation -> NO shuffle
// reduction, writes 1KB contiguous (gather1) / 64B-per-edge (gather2).
// Weights: 1/cnt over idx>0 slots; cnt==0 -> all slots are row 0 -> out=row0
// (== softmax over {1,-9e15} exactly; validated logic since r1).
// ---------------------------------------------------------------------------
template<int OUT_BF16>
__global__ __launch_bounds__(256) void gather_slice(
        const unsigned short* __restrict__ src, const int* __restrict__ idx,
        void* __restrict__ dst, int M) {
    const int b = blockIdx.x;
    const int slice = b & 7;
    const int tid = threadIdx.x;
    const int lane = tid & 63;
    const int wv = tid >> 6;
    const int sub = lane & 1;
    const int e_raw = (b >> 3) * 128 + wv * 32 + (lane >> 1);
    const int e = min(e_raw, M - 1);

    // my half of the edge's 32 indices (16 ints), non-temporal (single use)
    const i32x4* ib = (const i32x4*)(idx + (size_t)e * NPE + sub * 16);
    const i32x4 q0 = __builtin_nontemporal_load(ib + 0);
    const i32x4 q1 = __builtin_nontemporal_load(ib + 1);
    const i32x4 q2 = __builtin_nontemporal_load(ib + 2);
    const i32x4 q3 = __builtin_nontemporal_load(ib + 3);
    int idxr[16];
    idxr[0]=q0.x;  idxr[1]=q0.y;  idxr[2]=q0.z;  idxr[3]=q0.w;
    idxr[4]=q1.x;  idxr[5]=q1.y;  idxr[6]=q1.z;  idxr[7]=q1.w;
    idxr[8]=q2.x;  idxr[9]=q2.y;  idxr[10]=q2.z; idxr[11]=q2.w;
    idxr[12]=q3.x; idxr[13]=q3.y; idxr[14]=q3.z; idxr[15]=q3.w;

    // lane's 16 B sub-chunk of the slice: cols slice*16 + sub*8 .. +8
    const unsigned short* sbase = src + slice * SLICE_COLS + sub * 8;

    float acc[8] = {0.f,0.f,0.f,0.f,0.f,0.f,0.f,0.f};
    int cnt = 0;
    uint4 vlast = make_uint4(0, 0, 0, 0);
#pragma unroll
    for (int j = 0; j < 16; ++j) {
        const int ia = idxr[j];                 // lane0: idx[j], lane1: idx[16+j]
        const int ix = __shfl_xor(ia, 1);       // partner's
        const int idJ = (sub == 0) ? ia : ix;   // slot j
        const int idK = (sub == 0) ? ix : ia;   // slot j+16
        const uint4 vJ = *(const uint4*)(sbase + (size_t)idJ * D);
        const uint4 vK = *(const uint4*)(sbase + (size_t)idK * D);
        cnt += (idJ > 0) + (idK > 0);
        acc8(vJ, (idJ > 0) ? 1.f : 0.f, acc);
        acc8(vK, (idK > 0) ? 1.f : 0.f, acc);
        if (j == 15) vlast = vK;                // slot 31 (row 0 when cnt==0)
    }
    float scale;
    if (cnt > 0) scale = 1.f / (float)cnt;
    else { set8(vlast, acc); scale = 1.f; }

    if (e_raw < M) {
        if (OUT_BF16) {
            uint4 o;
            o.x = (unsigned)f2bf_bits(acc[0]*scale) | ((unsigned)f2bf_bits(acc[1]*scale) << 16);
            o.y = (unsigned)f2bf_bits(acc[2]*scale) | ((unsigned)f2bf_bits(acc[3]*scale) << 16);
            o.z = (unsigned)f2bf_bits(acc[4]*scale) | ((unsigned)f2bf_bits(acc[5]*scale) << 16);
            o.w = (unsigned)f2bf_bits(acc[6]*scale) | ((unsigned)f2bf_bits(acc[7]*scale) << 16);
            // sliced layout [NSLICE][M][16]: contiguous 1KB per wave
            *(uint4*)((unsigned short*)dst + ((size_t)slice * M + e) * SLICE_COLS + sub * 8) = o;
        } else {
            float* dp = (float*)dst + (size_t)e * D + slice * SLICE_COLS + sub * 8;
            *(float4*)dp = make_float4(acc[0]*scale, acc[1]*scale, acc[2]*scale, acc[3]*scale);
            *(float4*)(dp + 4) = make_float4(acc[4]*scale, acc[5]*scale, acc[6]*scale, acc[7]*scale);
        }
    }
}

// ---------------------------------------------------------------------------
// Fused double GEMM: e1[M,128] = bf16( relu(gxs @ W1) @ W2 ).  Same as r8
// (80 KB LDS -> 2 blk/CU, validated absmax) except the gx tile is read from
// the sliced gxs[8][M][16] layout (per-slice rows contiguous -> 128 B runs).
// ---------------------------------------------------------------------------
__global__ __launch_bounds__(256) void gemm12(const unsigned short* __restrict__ gxs,
                                              const unsigned short* __restrict__ Wt,
                                              unsigned short* __restrict__ e1, int M) {
    __shared__ unsigned short sW1[128 * 128];  // 32 KB (swizzled)
    __shared__ unsigned short sW2[128 * 128];  // 32 KB (swizzled)
    __shared__ unsigned short sA[64 * 128];    // 16 KB (swizzled; gx->t->out)
    const int tid = threadIdx.x;
    const int row0 = blockIdx.x * 64;
    const int nrows = min(64, M - row0);

    {
        const float4* w4 = (const float4*)Wt;
#pragma unroll
        for (int j = 0; j < 8; ++j) {
            const int i = tid + j * 256;            // 0..2047
            const int r = i >> 4, cc = (i & 15) * 16;
            *(float4*)((char*)sW1 + swz(r, cc)) = w4[i];
            *(float4*)((char*)sW2 + swz(r, cc)) = w4[2048 + i];
        }
    }
    {
#pragma unroll
        for (int j = 0; j < 4; ++j) {
            const int i = tid + j * 256;            // 0..1023
            const int r = i >> 4, c16 = i & 15;
            int gr = row0 + r; if (gr >= M) gr = M - 1;
            // sliced source: slice = c16>>1, half = c16&1 -> cols c16*8..+8
            const float4 v = *(const float4*)&gxs[((size_t)(c16 >> 1) * M + gr) * SLICE_COLS + (c16 & 1) * 8];
            *(float4*)((char*)sA + swz(r, c16 * 16)) = v;
        }
    }
    __syncthreads();

    const int lane = tid & 63;
    const int wv = tid >> 6;        // 0..3
    const int r16 = lane & 15;
    const int hi = lane >> 4;
    const int Ra = wv * 16 + r16;

    short8 af[4];
#pragma unroll
    for (int kt = 0; kt < 4; ++kt)
        af[kt] = *(const short8*)((char*)sA + swz(Ra, kt * 64 + hi * 16));

    f32x4 acc[8];
#pragma unroll
    for (int ct = 0; ct < 8; ++ct) acc[ct] = (f32x4){0.f, 0.f, 0.f, 0.f};
#pragma unroll
    for (int ct = 0; ct < 8; ++ct)
#pragma unroll
        for (int kt = 0; kt < 4; ++kt) {
            const short8 bf = *(const short8*)((char*)sW1 + swz(ct * 16 + r16, kt * 64 + hi * 16));
            acc[ct] = __builtin_amdgcn_mfma_f32_16x16x32_bf16(af[kt], bf, acc[ct], 0, 0, 0);
        }

#pragma unroll
    for (int ct = 0; ct < 8; ++ct)
#pragma unroll
        for (int i = 0; i < 4; ++i)
            *(unsigned short*)((char*)sA + swz(wv * 16 + hi * 4 + i, (ct * 16 + r16) * 2)) =
                f2bf_bits(fmaxf(acc[ct][i], 0.f));

    short8 af2[4];
#pragma unroll
    for (int kt = 0; kt < 4; ++kt)
        af2[kt] = *(const short8*)((char*)sA + swz(Ra, kt * 64 + hi * 16));

    f32x4 acc2[8];
#pragma unroll
    for (int ct = 0; ct < 8; ++ct) acc2[ct] = (f32x4){0.f, 0.f, 0.f, 0.f};
#pragma unroll
    for (int ct = 0; ct < 8; ++ct)
#pragma unroll
        for (int kt = 0; kt < 4; ++kt) {
            const short8 bf = *(const short8*)((char*)sW2 + swz(ct * 16 + r16, kt * 64 + hi * 16));
            acc2[ct] = __builtin_amdgcn_mfma_f32_16x16x32_bf16(af2[kt], bf, acc2[ct], 0, 0, 0);
        }

#pragma unroll
    for (int ct = 0; ct < 8; ++ct)
#pragma unroll
        for (int i = 0; i < 4; ++i)
            *(unsigned short*)((char*)sA + swz(wv * 16 + hi * 4 + i, (ct * 16 + r16) * 2)) =
                f2bf_bits(acc2[ct][i]);
    __syncthreads();

#pragma unroll
    for (int j = 0; j < 4; ++j) {
        const int i = tid + j * 256;                // 0..1023 16B chunks
        const int r = i >> 4, cc = i & 15;
        if (r < nrows)
            *(float4*)&e1[(size_t)(row0 + r) * D + cc * 8] =
                *(const float4*)((char*)sA + swz(r, cc * 16));
    }
}

extern "C" void kernel_launch(void* const* d_in, const int* in_sizes, int n_in,
                              void* d_out, int out_size, void* d_ws, size_t ws_size,
                              hipStream_t stream) {
    const float* x    = (const float*)d_in[0];   // [N,128] f32
    const int*   seq  = (const int*)d_in[1];     // [E,32] int32 (harness converts)
    const int*   useq = (const int*)d_in[3];     // [U,32] int32
    const float* w1   = (const float*)d_in[5];   // [128,128] f32
    const float* w2   = (const float*)d_in[6];   // [128,128] f32
    float* out = (float*)d_out;                  // [U,128] f32

    // workspace: Wt 64KB | xb bf16 25.6MB | gxs sliced bf16 12.8MB | e1 bf16 12.8MB
    unsigned short* wt  = (unsigned short*)d_ws;
    unsigned short* xb  = wt + 2 * 16384;
    unsigned short* gxs = xb + (size_t)N_NODES * D;
    unsigned short* e1  = gxs + (size_t)NSLICE * E_EDGES * SLICE_COLS;

    const int n8 = N_NODES * D / 8;
    prep<<<128 + (n8 + 255) / 256, 256, 0, stream>>>(w1, w2, x, wt, xb, n8);

    const int gchunks = (E_EDGES + 127) / 128;   // 128 edges per block
    // 1) gxs = bf16(masked_mean(xb[seq])), XCD-sliced
    gather_slice<1><<<gchunks * NSLICE, 256, 0, stream>>>(xb, seq, gxs, E_EDGES);

    // 2) e1 = bf16(relu(gxs @ W1) @ W2)
    gemm12<<<(E_EDGES + 63) / 64, 256, 0, stream>>>(gxs, wt, e1, E_EDGES);

    // 3) out = masked_mean(e1[useq]) (f32), XCD-sliced
    gather_slice<0><<<gchunks * NSLICE, 256, 0, stream>>>(e1, useq, out, U_NODES);
}